// Round 12
// baseline (116.933 us; speedup 1.0000x reference)
//
#include <hip/hip_runtime.h>

// NCC loss, fused z-sweep, v12 = R9 skeleton + TWO-SLICE batching:
// per barrier pair process slices (s,s+1): [st write x2] A [xf x2] B
// [preload x2 + yf x2 + ring x2 + NCC x2]. Independent work merged ->
// 2x ILP per phase, half the barriers; live state stays one pair.
// Ring slots literal via 9 pair-bodies / 18 slices, loop s0 in {0,18}.
// Grid 1600 x 256, LDS ~24.5 KB.

#define TX 16
#define TY 16
#define ZC 20
#define PH 24          // TY+8
#define PW 24          // TX+8
#define XFP 16         // float4 row stride
#define NSTEP 28       // ZC+8
#define NN 160
#define NPLANE (160*160)

__global__ void ncc_zero_ws(float* ws) { ws[0] = 0.0f; }

__global__ __launch_bounds__(256)
void ncc_fused(const float* __restrict__ pred, const float* __restrict__ target,
               float* __restrict__ ws) {
  __shared__ float2 st[2][PH * PW];      // staged planes        9.2 KB
  __shared__ float4 xf4[2][PH * XFP];    // x-filt 4 moments    12.3 KB
  __shared__ float  xf1[2][PH * XFP];    // x-filt tp            3.1 KB
  __shared__ float  wsum[4];

  const int tid = threadIdx.x;
  const int tx = tid & 15;
  const int ty = tid >> 4;               // 0..15

  int b = blockIdx.x;
  const int xt = b % 10; b /= 10;
  const int yt = b % 10; b /= 10;
  const int zc = b % 8;  b /= 8;
  const int x0 = xt * TX, y0 = yt * TY, z0 = zc * ZC;
  const size_t bbase = (size_t)b * (size_t)NN * (size_t)NPLANE;

  // ---- hoisted z-invariant stage geometry (3 strided positions) ----
  int soff0, soff1, soff2;
  bool sv0, sv1, sv2;
  {
    const int yy = tid / PW, xx = tid - yy * PW;
    const int gy = y0 + yy - 4, gx = x0 + xx - 4;
    sv0 = ((unsigned)gy < NN) && ((unsigned)gx < NN);
    soff0 = gy * NN + gx;
  }
  {
    const int pos = tid + 256;
    const int yy = pos / PW, xx = pos - yy * PW;
    const int gy = y0 + yy - 4, gx = x0 + xx - 4;
    sv1 = ((unsigned)gy < NN) && ((unsigned)gx < NN);
    soff1 = gy * NN + gx;
  }
  {
    const int pos = tid + 512;
    const int yy = pos / PW, xx = pos - yy * PW;
    const int gy = y0 + yy - 4, gx = x0 + xx - 4;
    sv2 = (tid < 64) && ((unsigned)gy < NN) && ((unsigned)gx < NN);
    soff2 = gy * NN + gx;
  }

  float rA0t, rA0p, rA1t, rA1p, rA2t, rA2p;   // prefetch, even slice
  float rB0t, rB0p, rB1t, rB1p, rB2t, rB2p;   // prefetch, odd slice

#define PRELOAD_A(SS) do {                                                    \
    const int zi_ = z0 - 4 + (SS);                                            \
    if ((unsigned)zi_ < NN) {                                                 \
      const size_t zb_ = bbase + (size_t)zi_ * (size_t)NPLANE;                \
      rA0t = sv0 ? target[zb_ + soff0] : 0.0f;                                \
      rA0p = sv0 ? pred[zb_ + soff0]   : 0.0f;                                \
      rA1t = sv1 ? target[zb_ + soff1] : 0.0f;                                \
      rA1p = sv1 ? pred[zb_ + soff1]   : 0.0f;                                \
      rA2t = sv2 ? target[zb_ + soff2] : 0.0f;                                \
      rA2p = sv2 ? pred[zb_ + soff2]   : 0.0f;                                \
    }                                                                         \
  } while (0)

#define PRELOAD_B(SS) do {                                                    \
    const int zi_ = z0 - 4 + (SS);                                            \
    if ((unsigned)zi_ < NN) {                                                 \
      const size_t zb_ = bbase + (size_t)zi_ * (size_t)NPLANE;                \
      rB0t = sv0 ? target[zb_ + soff0] : 0.0f;                                \
      rB0p = sv0 ? pred[zb_ + soff0]   : 0.0f;                                \
      rB1t = sv1 ? target[zb_ + soff1] : 0.0f;                                \
      rB1p = sv1 ? pred[zb_ + soff1]   : 0.0f;                                \
      rB2t = sv2 ? target[zb_ + soff2] : 0.0f;                                \
      rB2p = sv2 ? pred[zb_ + soff2]   : 0.0f;                                \
    }                                                                         \
  } while (0)

  // ---- 9-tap x-filter of one output (buffer J, row YY, col XX) ----
#define XFOUT(J, YY, XX) do {                                                 \
    float s_t = 0, s_p = 0, s_t2 = 0, s_p2 = 0, s_tp = 0;                     \
    _Pragma("unroll")                                                         \
    for (int dx = 0; dx < 9; ++dx) {                                          \
      const float2 v = st[J][(YY) * PW + (XX) + dx];                          \
      s_t += v.x;                                                             \
      s_p += v.y;                                                             \
      s_t2 = fmaf(v.x, v.x, s_t2);                                            \
      s_p2 = fmaf(v.y, v.y, s_p2);                                            \
      s_tp = fmaf(v.x, v.y, s_tp);                                            \
    }                                                                         \
    xf4[J][(YY) * XFP + (XX)] = make_float4(s_t, s_p, s_t2, s_p2);            \
    xf1[J][(YY) * XFP + (XX)] = s_tp;                                         \
  } while (0)

  float buf0[9], buf1[9], buf2[9], buf3[9], buf4[9];
  float run0 = 0, run1 = 0, run2 = 0, run3 = 0, run4 = 0;
  #pragma unroll
  for (int j = 0; j < 9; ++j) { buf0[j]=0; buf1[j]=0; buf2[j]=0; buf3[j]=0; buf4[j]=0; }
  float acc = 0.0f;
  const float inv_kvol = 1.0f / 729.0f;

  // ---- yf + ring + NCC for slice S_ from buffer J, literal SLOT ----
#define CONSUME(J, SLOT, S_) do {                                             \
    if ((S_) < NSTEP) {                                                       \
      float c0 = 0, c1 = 0, c2 = 0, c3 = 0, c4 = 0;                           \
      if ((unsigned)(z0 - 4 + (S_)) < NN) {                                   \
        _Pragma("unroll")                                                     \
        for (int dy = 0; dy < 9; ++dy) {                                      \
          const float4 a = xf4[J][(ty + dy) * XFP + tx];                      \
          const float  c = xf1[J][(ty + dy) * XFP + tx];                      \
          c0 += a.x; c1 += a.y; c2 += a.z; c3 += a.w; c4 += c;                \
        }                                                                     \
      }                                                                       \
      run0 += c0 - buf0[(SLOT)]; buf0[(SLOT)] = c0;                           \
      run1 += c1 - buf1[(SLOT)]; buf1[(SLOT)] = c1;                           \
      run2 += c2 - buf2[(SLOT)]; buf2[(SLOT)] = c2;                           \
      run3 += c3 - buf3[(SLOT)]; buf3[(SLOT)] = c3;                           \
      run4 += c4 - buf4[(SLOT)]; buf4[(SLOT)] = c4;                           \
      if ((S_) >= 8) {                                                        \
        const float tavg = run0 * inv_kvol;                                   \
        const float pavg = run1 * inv_kvol;                                   \
        const float cross = run4 - pavg * run0;                               \
        const float tvar  = run2 - tavg * run0;                               \
        const float pvar  = run3 - pavg * run1;                               \
        acc += (cross * cross) / (tvar * pvar + 1e-5f);                       \
      }                                                                       \
    }                                                                         \
  } while (0)

  // ---- pair body: slices (s, s+1); SA/SB = literal ring slots ----
#define PBODY(KK, SA, SB) do {                                                \
    const int s_ = s0 + 2 * (KK);                                             \
    const bool p0_ = (s_ < NSTEP) && ((unsigned)(z0 - 4 + s_) < NN);          \
    const bool p1_ = (s_ + 1 < NSTEP) && ((unsigned)(z0 - 3 + s_) < NN);      \
    if (p0_) {                                                                \
      st[0][tid]       = make_float2(rA0t, rA0p);                             \
      st[0][tid + 256] = make_float2(rA1t, rA1p);                             \
      if (tid < 64) st[0][tid + 512] = make_float2(rA2t, rA2p);               \
    }                                                                         \
    if (p1_) {                                                                \
      st[1][tid]       = make_float2(rB0t, rB0p);                             \
      st[1][tid + 256] = make_float2(rB1t, rB1p);                             \
      if (tid < 64) st[1][tid + 512] = make_float2(rB2t, rB2p);               \
    }                                                                         \
    __syncthreads();   /* A: st[0..1] visible */                              \
    if (p0_) { XFOUT(0, ty, tx); if (tid < 128) XFOUT(0, 16 + ty, tx); }      \
    if (p1_) { XFOUT(1, ty, tx); if (tid < 128) XFOUT(1, 16 + ty, tx); }      \
    __syncthreads();   /* B: xf[0..1] visible; st reads done */               \
    if (s_ + 2 < NSTEP) { PRELOAD_A(s_ + 2); }                                \
    if (s_ + 3 < NSTEP) { PRELOAD_B(s_ + 3); }                                \
    CONSUME(0, SA, s_);                                                       \
    CONSUME(1, SB, s_ + 1);                                                   \
  } while (0)

  // ---- prologue: issue loads for slices 0,1 ----
  PRELOAD_A(0);
  PRELOAD_B(1);

  // 9 pair-bodies cover 18 slices with slot = s%9; two loop iterations
  for (int s0 = 0; s0 < NSTEP; s0 += 18) {
    PBODY(0, 0, 1); PBODY(1, 2, 3); PBODY(2, 4, 5); PBODY(3, 6, 7);
    PBODY(4, 8, 0); PBODY(5, 1, 2); PBODY(6, 3, 4); PBODY(7, 5, 6);
    PBODY(8, 7, 8);
  }
#undef PBODY
#undef CONSUME
#undef XFOUT
#undef PRELOAD_A
#undef PRELOAD_B

  // ---- reduction: wave shuffle -> LDS -> one atomicAdd per block ----
  #pragma unroll
  for (int off = 32; off > 0; off >>= 1)
    acc += __shfl_down(acc, off, 64);
  if ((tid & 63) == 0) wsum[tid >> 6] = acc;
  __syncthreads();
  if (tid == 0) {
    float tot = wsum[0] + wsum[1] + wsum[2] + wsum[3];
    atomicAdd(ws, tot);
  }
}

__global__ void ncc_finalize(const float* __restrict__ ws, float* __restrict__ out) {
  out[0] = -ws[0] * (1.0f / 8192000.0f);
}

extern "C" void kernel_launch(void* const* d_in, const int* in_sizes, int n_in,
                              void* d_out, int out_size, void* d_ws, size_t ws_size,
                              hipStream_t stream) {
  const float* pred   = (const float*)d_in[0];
  const float* target = (const float*)d_in[1];
  float* out = (float*)d_out;
  float* ws  = (float*)d_ws;

  ncc_zero_ws<<<1, 1, 0, stream>>>(ws);
  // grid: 10 x-tiles * 10 y-tiles * 8 z-chunks * 2 batches = 1600 blocks
  ncc_fused<<<1600, 256, 0, stream>>>(pred, target, ws);
  ncc_finalize<<<1, 1, 0, stream>>>(ws, out);
}

// Round 13
// 100.294 us; speedup vs baseline: 1.1659x; 1.1659x over previous
//
#include <hip/hip_runtime.h>

// NCC loss, fused z-sweep, v13 = R9 EXACT structure at 2x block count:
// 128-thread blocks, 16(x) x 8(y) tile, grid 3200 (~12.5 blocks/CU).
// Same byte-stride classes as R9 (st rows 192 B, xf rows 256 B; measured
// ~0 conflicts), same 3 stage positions/thread, same T14 reg-prefetch,
// same loop-of-9 literal ring slots, 2 barriers/slice. LDS ~8.2 KB.

#define TX 16
#define TY 8
#define ZC 20
#define PH 16          // TY+8
#define PW 24          // TX+8
#define XFP 16         // float4 row stride
#define NSTEP 28       // ZC+8
#define NN 160
#define NPLANE (160*160)

__global__ void ncc_zero_ws(float* ws) { ws[0] = 0.0f; }

__global__ __launch_bounds__(128)
void ncc_fused(const float* __restrict__ pred, const float* __restrict__ target,
               float* __restrict__ ws) {
  __shared__ float2 st[PH * PW];       // staged (t,p)          3.0 KB
  __shared__ float4 xf4[PH * XFP];     // x-filt (t,p,t2,p2)    4.0 KB
  __shared__ float  xf1[PH * XFP];     // x-filt tp             1.0 KB
  __shared__ float  wsum[2];

  const int tid = threadIdx.x;         // 0..127
  const int tx = tid & 15;
  const int ty = tid >> 4;             // 0..7

  int b = blockIdx.x;
  const int xt = b % 10; b /= 10;
  const int yt = b % 20; b /= 20;
  const int zc = b % 8;  b /= 8;
  const int x0 = xt * TX, y0 = yt * TY, z0 = zc * ZC;
  const size_t bbase = (size_t)b * (size_t)NN * (size_t)NPLANE;

  // ---- hoisted z-invariant stage geometry (3 strided positions, 384=3x128) ----
  int soff0, soff1, soff2;
  bool sv0, sv1, sv2;
  {
    const int yy = tid / PW, xx = tid - yy * PW;
    const int gy = y0 + yy - 4, gx = x0 + xx - 4;
    sv0 = ((unsigned)gy < NN) && ((unsigned)gx < NN);
    soff0 = gy * NN + gx;
  }
  {
    const int pos = tid + 128;
    const int yy = pos / PW, xx = pos - yy * PW;
    const int gy = y0 + yy - 4, gx = x0 + xx - 4;
    sv1 = ((unsigned)gy < NN) && ((unsigned)gx < NN);
    soff1 = gy * NN + gx;
  }
  {
    const int pos = tid + 256;
    const int yy = pos / PW, xx = pos - yy * PW;
    const int gy = y0 + yy - 4, gx = x0 + xx - 4;
    sv2 = ((unsigned)gy < NN) && ((unsigned)gx < NN);
    soff2 = gy * NN + gx;
  }

  float rt0, rp0, rt1, rp1, rt2, rp2;  // prefetch regs (named -> static)

#define PRELOAD(SS) do {                                                      \
    const int zi_ = z0 - 4 + (SS);                                            \
    if ((unsigned)zi_ < NN) {                                                 \
      const size_t zb_ = bbase + (size_t)zi_ * (size_t)NPLANE;                \
      rt0 = sv0 ? target[zb_ + soff0] : 0.0f;                                 \
      rp0 = sv0 ? pred[zb_ + soff0]   : 0.0f;                                 \
      rt1 = sv1 ? target[zb_ + soff1] : 0.0f;                                 \
      rp1 = sv1 ? pred[zb_ + soff1]   : 0.0f;                                 \
      rt2 = sv2 ? target[zb_ + soff2] : 0.0f;                                 \
      rp2 = sv2 ? pred[zb_ + soff2]   : 0.0f;                                 \
    }                                                                         \
  } while (0)

  // ---- 9-tap x-filter of one output (row YY, col XX) ----
#define XFOUT(YY, XX) do {                                                    \
    float s_t = 0, s_p = 0, s_t2 = 0, s_p2 = 0, s_tp = 0;                     \
    _Pragma("unroll")                                                         \
    for (int dx = 0; dx < 9; ++dx) {                                          \
      const float2 v = st[(YY) * PW + (XX) + dx];                             \
      s_t += v.x;                                                             \
      s_p += v.y;                                                             \
      s_t2 = fmaf(v.x, v.x, s_t2);                                            \
      s_p2 = fmaf(v.y, v.y, s_p2);                                            \
      s_tp = fmaf(v.x, v.y, s_tp);                                            \
    }                                                                         \
    xf4[(YY) * XFP + (XX)] = make_float4(s_t, s_p, s_t2, s_p2);               \
    xf1[(YY) * XFP + (XX)] = s_tp;                                            \
  } while (0)

  float buf0[9], buf1[9], buf2[9], buf3[9], buf4[9];
  float run0 = 0, run1 = 0, run2 = 0, run3 = 0, run4 = 0;
  #pragma unroll
  for (int j = 0; j < 9; ++j) { buf0[j]=0; buf1[j]=0; buf2[j]=0; buf3[j]=0; buf4[j]=0; }
  float acc = 0.0f;
  const float inv_kvol = 1.0f / 729.0f;

  // ---- slice body; PP literal -> static ring indexing (rule #20) ----
#define ZBODY(PP) do {                                                        \
    const int s = s0 + (PP);                                                  \
    if (s < NSTEP) {                                                          \
      const int zi = z0 - 4 + s;                                              \
      const bool zvalid = ((unsigned)zi < NN);    /* block-uniform */         \
      float cur0 = 0, cur1 = 0, cur2 = 0, cur3 = 0, cur4 = 0;                 \
      if (zvalid) {                                                           \
        /* write st from prefetch regs (loaded last body) */                  \
        st[tid]       = make_float2(rt0, rp0);                                \
        st[tid + 128] = make_float2(rt1, rp1);                                \
        st[tid + 256] = make_float2(rt2, rp2);                                \
        __syncthreads();   /* A: st visible */                                \
        XFOUT(ty, tx);                 /* rows 0..7  */                       \
        XFOUT(ty + 8, tx);             /* rows 8..15 */                       \
        __syncthreads();   /* B: xf visible; st reads done */                 \
      }                                                                       \
      /* T14: issue next slice's loads; complete during yf+ring+NCC */        \
      if (s + 1 < NSTEP) { PRELOAD(s + 1); }                                  \
      if (zvalid) {                                                           \
        _Pragma("unroll")                                                     \
        for (int dy = 0; dy < 9; ++dy) {                                      \
          const float4 a = xf4[(ty + dy) * XFP + tx];                         \
          const float  c = xf1[(ty + dy) * XFP + tx];                         \
          cur0 += a.x; cur1 += a.y; cur2 += a.z; cur3 += a.w; cur4 += c;      \
        }                                                                     \
      }                                                                       \
      run0 += cur0 - buf0[(PP)]; buf0[(PP)] = cur0;                           \
      run1 += cur1 - buf1[(PP)]; buf1[(PP)] = cur1;                           \
      run2 += cur2 - buf2[(PP)]; buf2[(PP)] = cur2;                           \
      run3 += cur3 - buf3[(PP)]; buf3[(PP)] = cur3;                           \
      run4 += cur4 - buf4[(PP)]; buf4[(PP)] = cur4;                           \
      if (s >= 8) {                                                           \
        const float tavg = run0 * inv_kvol;                                   \
        const float pavg = run1 * inv_kvol;                                   \
        const float cross = run4 - pavg * run0;                               \
        const float tvar  = run2 - tavg * run0;                               \
        const float pvar  = run3 - pavg * run1;                               \
        acc += (cross * cross) / (tvar * pvar + 1e-5f);                       \
      }                                                                       \
    }                                                                         \
  } while (0)

  // ---- prologue: issue loads for slice 0 ----
  PRELOAD(0);

  for (int s0 = 0; s0 < NSTEP; s0 += 9) {
    ZBODY(0); ZBODY(1); ZBODY(2); ZBODY(3); ZBODY(4);
    ZBODY(5); ZBODY(6); ZBODY(7); ZBODY(8);
  }
#undef ZBODY
#undef XFOUT
#undef PRELOAD

  // ---- reduction: wave shuffle -> LDS -> one atomicAdd per block ----
  #pragma unroll
  for (int off = 32; off > 0; off >>= 1)
    acc += __shfl_down(acc, off, 64);
  if ((tid & 63) == 0) wsum[tid >> 6] = acc;
  __syncthreads();
  if (tid == 0) {
    float tot = wsum[0] + wsum[1];
    atomicAdd(ws, tot);
  }
}

__global__ void ncc_finalize(const float* __restrict__ ws, float* __restrict__ out) {
  out[0] = -ws[0] * (1.0f / 8192000.0f);
}

extern "C" void kernel_launch(void* const* d_in, const int* in_sizes, int n_in,
                              void* d_out, int out_size, void* d_ws, size_t ws_size,
                              hipStream_t stream) {
  const float* pred   = (const float*)d_in[0];
  const float* target = (const float*)d_in[1];
  float* out = (float*)d_out;
  float* ws  = (float*)d_ws;

  ncc_zero_ws<<<1, 1, 0, stream>>>(ws);
  // grid: 10 x-tiles * 20 y-tiles * 8 z-chunks * 2 batches = 3200 blocks
  ncc_fused<<<3200, 128, 0, stream>>>(pred, target, ws);
  ncc_finalize<<<1, 1, 0, stream>>>(ws, out);
}

// Round 14
// 80.127 us; speedup vs baseline: 1.4593x; 1.2517x over previous
//
#include <hip/hip_runtime.h>

// NCC loss, fused z-sweep, v14 = R9 EXACT structure with ZC=40:
// halves the z-halo overhead (28/20 -> 48/40 slices per output slice).
// 256 threads, 16x16 tile, grid 800 (~3.1 blocks/CU), LDS ~12.6 KB,
// T14 reg-prefetch, loop-of-9 literal ring slots, 2 barriers/slice.

#define TX 16
#define TY 16
#define ZC 40
#define PH 24          // TY+8
#define PW 24          // TX+8
#define XFP 16         // float4 row stride
#define NSTEP 48       // ZC+8
#define NN 160
#define NPLANE (160*160)

__global__ void ncc_zero_ws(float* ws) { ws[0] = 0.0f; }

__global__ __launch_bounds__(256)
void ncc_fused(const float* __restrict__ pred, const float* __restrict__ target,
               float* __restrict__ ws) {
  __shared__ float2 st[PH * PW];       // staged (t,p)          4.6 KB
  __shared__ float4 xf4[PH * XFP];     // x-filt (t,p,t2,p2)    6.1 KB
  __shared__ float  xf1[PH * XFP];     // x-filt tp             1.5 KB
  __shared__ float  wsum[4];

  const int tid = threadIdx.x;
  const int tx = tid & 15;
  const int ty = tid >> 4;             // 0..15

  int b = blockIdx.x;
  const int xt = b % 10; b /= 10;
  const int yt = b % 10; b /= 10;
  const int zc = b % 4;  b /= 4;
  const int x0 = xt * TX, y0 = yt * TY, z0 = zc * ZC;
  const size_t bbase = (size_t)b * (size_t)NN * (size_t)NPLANE;

  // ---- hoisted z-invariant stage geometry (3 strided positions) ----
  int soff0, soff1, soff2;
  bool sv0, sv1, sv2;
  {
    const int yy = tid / PW, xx = tid - yy * PW;
    const int gy = y0 + yy - 4, gx = x0 + xx - 4;
    sv0 = ((unsigned)gy < NN) && ((unsigned)gx < NN);
    soff0 = gy * NN + gx;
  }
  {
    const int pos = tid + 256;
    const int yy = pos / PW, xx = pos - yy * PW;
    const int gy = y0 + yy - 4, gx = x0 + xx - 4;
    sv1 = ((unsigned)gy < NN) && ((unsigned)gx < NN);
    soff1 = gy * NN + gx;
  }
  {
    const int pos = tid + 512;
    const int yy = pos / PW, xx = pos - yy * PW;
    const int gy = y0 + yy - 4, gx = x0 + xx - 4;
    sv2 = (tid < 64) && ((unsigned)gy < NN) && ((unsigned)gx < NN);
    soff2 = gy * NN + gx;
  }

  float rt0, rp0, rt1, rp1, rt2, rp2;  // prefetch regs (named -> static)

#define PRELOAD(SS) do {                                                      \
    const int zi_ = z0 - 4 + (SS);                                            \
    if ((unsigned)zi_ < NN) {                                                 \
      const size_t zb_ = bbase + (size_t)zi_ * (size_t)NPLANE;                \
      rt0 = sv0 ? target[zb_ + soff0] : 0.0f;                                 \
      rp0 = sv0 ? pred[zb_ + soff0]   : 0.0f;                                 \
      rt1 = sv1 ? target[zb_ + soff1] : 0.0f;                                 \
      rp1 = sv1 ? pred[zb_ + soff1]   : 0.0f;                                 \
      rt2 = sv2 ? target[zb_ + soff2] : 0.0f;                                 \
      rp2 = sv2 ? pred[zb_ + soff2]   : 0.0f;                                 \
    }                                                                         \
  } while (0)

  // ---- 9-tap x-filter of one output (row YY, col XX) ----
#define XFOUT(YY, XX) do {                                                    \
    float s_t = 0, s_p = 0, s_t2 = 0, s_p2 = 0, s_tp = 0;                     \
    _Pragma("unroll")                                                         \
    for (int dx = 0; dx < 9; ++dx) {                                          \
      const float2 v = st[(YY) * PW + (XX) + dx];                             \
      s_t += v.x;                                                             \
      s_p += v.y;                                                             \
      s_t2 = fmaf(v.x, v.x, s_t2);                                            \
      s_p2 = fmaf(v.y, v.y, s_p2);                                            \
      s_tp = fmaf(v.x, v.y, s_tp);                                            \
    }                                                                         \
    xf4[(YY) * XFP + (XX)] = make_float4(s_t, s_p, s_t2, s_p2);               \
    xf1[(YY) * XFP + (XX)] = s_tp;                                            \
  } while (0)

  float buf0[9], buf1[9], buf2[9], buf3[9], buf4[9];
  float run0 = 0, run1 = 0, run2 = 0, run3 = 0, run4 = 0;
  #pragma unroll
  for (int j = 0; j < 9; ++j) { buf0[j]=0; buf1[j]=0; buf2[j]=0; buf3[j]=0; buf4[j]=0; }
  float acc = 0.0f;
  const float inv_kvol = 1.0f / 729.0f;

  // ---- slice body; PP literal -> static ring indexing (rule #20) ----
#define ZBODY(PP) do {                                                        \
    const int s = s0 + (PP);                                                  \
    if (s < NSTEP) {                                                          \
      const int zi = z0 - 4 + s;                                              \
      const bool zvalid = ((unsigned)zi < NN);    /* block-uniform */         \
      float cur0 = 0, cur1 = 0, cur2 = 0, cur3 = 0, cur4 = 0;                 \
      if (zvalid) {                                                           \
        /* write st from prefetch regs (loaded last body) */                  \
        st[tid]       = make_float2(rt0, rp0);                                \
        st[tid + 256] = make_float2(rt1, rp1);                                \
        if (tid < 64) st[tid + 512] = make_float2(rt2, rp2);                  \
        __syncthreads();   /* A: st visible */                                \
        for (int pos = tid; pos < PH * TX; pos += 256) {                      \
          const int yy = pos >> 4;                                            \
          const int xx = pos & 15;                                            \
          XFOUT(yy, xx);                                                      \
        }                                                                     \
        __syncthreads();   /* B: xf visible; st reads done */                 \
      }                                                                       \
      /* T14: issue next slice's loads; complete during yf+ring+NCC */        \
      if (s + 1 < NSTEP) { PRELOAD(s + 1); }                                  \
      if (zvalid) {                                                           \
        _Pragma("unroll")                                                     \
        for (int dy = 0; dy < 9; ++dy) {                                      \
          const float4 a = xf4[(ty + dy) * XFP + tx];                         \
          const float  c = xf1[(ty + dy) * XFP + tx];                         \
          cur0 += a.x; cur1 += a.y; cur2 += a.z; cur3 += a.w; cur4 += c;      \
        }                                                                     \
      }                                                                       \
      run0 += cur0 - buf0[(PP)]; buf0[(PP)] = cur0;                           \
      run1 += cur1 - buf1[(PP)]; buf1[(PP)] = cur1;                           \
      run2 += cur2 - buf2[(PP)]; buf2[(PP)] = cur2;                           \
      run3 += cur3 - buf3[(PP)]; buf3[(PP)] = cur3;                           \
      run4 += cur4 - buf4[(PP)]; buf4[(PP)] = cur4;                           \
      if (s >= 8) {                                                           \
        const float tavg = run0 * inv_kvol;                                   \
        const float pavg = run1 * inv_kvol;                                   \
        const float cross = run4 - pavg * run0;                               \
        const float tvar  = run2 - tavg * run0;                               \
        const float pvar  = run3 - pavg * run1;                               \
        acc += (cross * cross) / (tvar * pvar + 1e-5f);                       \
      }                                                                       \
    }                                                                         \
  } while (0)

  // ---- prologue: issue loads for slice 0 ----
  PRELOAD(0);

  // 48 slices: loop-of-9 with guards (slot = s % 9 since stride 9)
  for (int s0 = 0; s0 < NSTEP; s0 += 9) {
    ZBODY(0); ZBODY(1); ZBODY(2); ZBODY(3); ZBODY(4);
    ZBODY(5); ZBODY(6); ZBODY(7); ZBODY(8);
  }
#undef ZBODY
#undef XFOUT
#undef PRELOAD

  // ---- reduction: wave shuffle -> LDS -> one atomicAdd per block ----
  #pragma unroll
  for (int off = 32; off > 0; off >>= 1)
    acc += __shfl_down(acc, off, 64);
  if ((tid & 63) == 0) wsum[tid >> 6] = acc;
  __syncthreads();
  if (tid == 0) {
    float tot = wsum[0] + wsum[1] + wsum[2] + wsum[3];
    atomicAdd(ws, tot);
  }
}

__global__ void ncc_finalize(const float* __restrict__ ws, float* __restrict__ out) {
  out[0] = -ws[0] * (1.0f / 8192000.0f);
}

extern "C" void kernel_launch(void* const* d_in, const int* in_sizes, int n_in,
                              void* d_out, int out_size, void* d_ws, size_t ws_size,
                              hipStream_t stream) {
  const float* pred   = (const float*)d_in[0];
  const float* target = (const float*)d_in[1];
  float* out = (float*)d_out;
  float* ws  = (float*)d_ws;

  ncc_zero_ws<<<1, 1, 0, stream>>>(ws);
  // grid: 10 x-tiles * 10 y-tiles * 4 z-chunks * 2 batches = 800 blocks
  ncc_fused<<<800, 256, 0, stream>>>(pred, target, ws);
  ncc_finalize<<<1, 1, 0, stream>>>(ws, out);
}

// Round 15
// 78.525 us; speedup vs baseline: 1.4891x; 1.0204x over previous
//
#include <hip/hip_runtime.h>

// NCC loss, fused z-sweep, v15 = R14 (ZC=40, 16x16, T14 prefetch, literal
// ring) + packed-FP32 arithmetic: (t,p) and (t2,p2) moment pairs held as
// ext_vector float2 so hipcc emits v_pk_add_f32 / v_pk_fma_f32 (2 FLOPs per
// instr). xf: 5->3 VALU/tap, yf: 5->3 VALU/tap, ring+NCC packed likewise.
// Grid 800 x 256, LDS ~12.6 KB.

typedef float v2f __attribute__((ext_vector_type(2)));
typedef float v4f __attribute__((ext_vector_type(4)));

#define TX 16
#define TY 16
#define ZC 40
#define PH 24          // TY+8
#define PW 24          // TX+8
#define XFP 16         // v4f row stride
#define NSTEP 48       // ZC+8
#define NN 160
#define NPLANE (160*160)

__global__ void ncc_zero_ws(float* ws) { ws[0] = 0.0f; }

__global__ __launch_bounds__(256)
void ncc_fused(const float* __restrict__ pred, const float* __restrict__ target,
               float* __restrict__ ws) {
  __shared__ v2f st[PH * PW];          // staged (t,p)          4.6 KB
  __shared__ v4f xf4[PH * XFP];        // x-filt (t,p,t2,p2)    6.1 KB
  __shared__ float xf1[PH * XFP];      // x-filt tp             1.5 KB
  __shared__ float wsum[4];

  const int tid = threadIdx.x;
  const int tx = tid & 15;
  const int ty = tid >> 4;             // 0..15

  int b = blockIdx.x;
  const int xt = b % 10; b /= 10;
  const int yt = b % 10; b /= 10;
  const int zc = b % 4;  b /= 4;
  const int x0 = xt * TX, y0 = yt * TY, z0 = zc * ZC;
  const size_t bbase = (size_t)b * (size_t)NN * (size_t)NPLANE;

  // ---- hoisted z-invariant stage geometry (3 strided positions) ----
  int soff0, soff1, soff2;
  bool sv0, sv1, sv2;
  {
    const int yy = tid / PW, xx = tid - yy * PW;
    const int gy = y0 + yy - 4, gx = x0 + xx - 4;
    sv0 = ((unsigned)gy < NN) && ((unsigned)gx < NN);
    soff0 = gy * NN + gx;
  }
  {
    const int pos = tid + 256;
    const int yy = pos / PW, xx = pos - yy * PW;
    const int gy = y0 + yy - 4, gx = x0 + xx - 4;
    sv1 = ((unsigned)gy < NN) && ((unsigned)gx < NN);
    soff1 = gy * NN + gx;
  }
  {
    const int pos = tid + 512;
    const int yy = pos / PW, xx = pos - yy * PW;
    const int gy = y0 + yy - 4, gx = x0 + xx - 4;
    sv2 = (tid < 64) && ((unsigned)gy < NN) && ((unsigned)gx < NN);
    soff2 = gy * NN + gx;
  }

  float rt0, rp0, rt1, rp1, rt2, rp2;  // prefetch regs (named -> static)

#define PRELOAD(SS) do {                                                      \
    const int zi_ = z0 - 4 + (SS);                                            \
    if ((unsigned)zi_ < NN) {                                                 \
      const size_t zb_ = bbase + (size_t)zi_ * (size_t)NPLANE;                \
      rt0 = sv0 ? target[zb_ + soff0] : 0.0f;                                 \
      rp0 = sv0 ? pred[zb_ + soff0]   : 0.0f;                                 \
      rt1 = sv1 ? target[zb_ + soff1] : 0.0f;                                 \
      rp1 = sv1 ? pred[zb_ + soff1]   : 0.0f;                                 \
      rt2 = sv2 ? target[zb_ + soff2] : 0.0f;                                 \
      rp2 = sv2 ? pred[zb_ + soff2]   : 0.0f;                                 \
    }                                                                         \
  } while (0)

  // ---- 9-tap x-filter, packed: pk_add + pk_fma + fma per tap ----
#define XFOUT(YY, XX) do {                                                    \
    v2f m01 = {0.0f, 0.0f};                                                   \
    v2f m23 = {0.0f, 0.0f};                                                   \
    float s_tp = 0.0f;                                                        \
    _Pragma("unroll")                                                         \
    for (int dx = 0; dx < 9; ++dx) {                                          \
      const v2f v = st[(YY) * PW + (XX) + dx];                                \
      m01 += v;                                                               \
      m23 = __builtin_elementwise_fma(v, v, m23);                             \
      s_tp = fmaf(v.x, v.y, s_tp);                                            \
    }                                                                         \
    v4f o_; o_.x = m01.x; o_.y = m01.y; o_.z = m23.x; o_.w = m23.y;           \
    xf4[(YY) * XFP + (XX)] = o_;                                              \
    xf1[(YY) * XFP + (XX)] = s_tp;                                            \
  } while (0)

  v2f b01[9], b23[9];
  float b4[9];
  v2f run01 = {0.0f, 0.0f}, run23 = {0.0f, 0.0f};
  float run4 = 0.0f;
  #pragma unroll
  for (int j = 0; j < 9; ++j) {
    b01[j] = (v2f){0.0f, 0.0f}; b23[j] = (v2f){0.0f, 0.0f}; b4[j] = 0.0f;
  }
  float acc = 0.0f;
  const float inv_kvol = 1.0f / 729.0f;

  // ---- slice body; PP literal -> static ring indexing (rule #20) ----
#define ZBODY(PP) do {                                                        \
    const int s = s0 + (PP);                                                  \
    if (s < NSTEP) {                                                          \
      const int zi = z0 - 4 + s;                                              \
      const bool zvalid = ((unsigned)zi < NN);    /* block-uniform */         \
      v2f c01 = {0.0f, 0.0f}, c23 = {0.0f, 0.0f};                             \
      float c4 = 0.0f;                                                        \
      if (zvalid) {                                                           \
        v2f w_;                                                               \
        w_.x = rt0; w_.y = rp0; st[tid] = w_;                                 \
        w_.x = rt1; w_.y = rp1; st[tid + 256] = w_;                           \
        if (tid < 64) { w_.x = rt2; w_.y = rp2; st[tid + 512] = w_; }         \
        __syncthreads();   /* A: st visible */                                \
        for (int pos = tid; pos < PH * TX; pos += 256) {                      \
          const int yy = pos >> 4;                                            \
          const int xx = pos & 15;                                            \
          XFOUT(yy, xx);                                                      \
        }                                                                     \
        __syncthreads();   /* B: xf visible; st reads done */                 \
      }                                                                       \
      /* T14: issue next slice's loads; complete during yf+ring+NCC */        \
      if (s + 1 < NSTEP) { PRELOAD(s + 1); }                                  \
      if (zvalid) {                                                           \
        v4f a4 = {0.0f, 0.0f, 0.0f, 0.0f};                                    \
        _Pragma("unroll")                                                     \
        for (int dy = 0; dy < 9; ++dy) {                                      \
          a4 += xf4[(ty + dy) * XFP + tx];        /* 2x v_pk_add_f32 */       \
          c4 += xf1[(ty + dy) * XFP + tx];                                    \
        }                                                                     \
        c01.x = a4.x; c01.y = a4.y; c23.x = a4.z; c23.y = a4.w;               \
      }                                                                       \
      run01 += c01 - b01[(PP)]; b01[(PP)] = c01;                              \
      run23 += c23 - b23[(PP)]; b23[(PP)] = c23;                              \
      run4  += c4  - b4[(PP)];  b4[(PP)]  = c4;                               \
      if (s >= 8) {                                                           \
        const v2f avg = run01 * inv_kvol;                                     \
        const v2f var = __builtin_elementwise_fma(-avg, run01, run23);        \
        const float cross = fmaf(-avg.y, run01.x, run4);                      \
        acc += (cross * cross) / (var.x * var.y + 1e-5f);                     \
      }                                                                       \
    }                                                                         \
  } while (0)

  // ---- prologue: issue loads for slice 0 ----
  PRELOAD(0);

  // 48 slices: loop-of-9 (slot = s % 9 since stride 9)
  for (int s0 = 0; s0 < NSTEP; s0 += 9) {
    ZBODY(0); ZBODY(1); ZBODY(2); ZBODY(3); ZBODY(4);
    ZBODY(5); ZBODY(6); ZBODY(7); ZBODY(8);
  }
#undef ZBODY
#undef XFOUT
#undef PRELOAD

  // ---- reduction: wave shuffle -> LDS -> one atomicAdd per block ----
  #pragma unroll
  for (int off = 32; off > 0; off >>= 1)
    acc += __shfl_down(acc, off, 64);
  if ((tid & 63) == 0) wsum[tid >> 6] = acc;
  __syncthreads();
  if (tid == 0) {
    float tot = wsum[0] + wsum[1] + wsum[2] + wsum[3];
    atomicAdd(ws, tot);
  }
}

__global__ void ncc_finalize(const float* __restrict__ ws, float* __restrict__ out) {
  out[0] = -ws[0] * (1.0f / 8192000.0f);
}

extern "C" void kernel_launch(void* const* d_in, const int* in_sizes, int n_in,
                              void* d_out, int out_size, void* d_ws, size_t ws_size,
                              hipStream_t stream) {
  const float* pred   = (const float*)d_in[0];
  const float* target = (const float*)d_in[1];
  float* out = (float*)d_out;
  float* ws  = (float*)d_ws;

  ncc_zero_ws<<<1, 1, 0, stream>>>(ws);
  // grid: 10 x-tiles * 10 y-tiles * 4 z-chunks * 2 batches = 800 blocks
  ncc_fused<<<800, 256, 0, stream>>>(pred, target, ws);
  ncc_finalize<<<1, 1, 0, stream>>>(ws, out);
}